// Round 11
// baseline (130.839 us; speedup 1.0000x reference)
//
#include <hip/hip_runtime.h>

// out[128,16384] = [A|B](128x8384) @ [x; x2](8384x16384), fp16 MFMA.
// Round 20 = decomposition change: 256-thread blocks, 64x64 tile, FULL K.
// Cross-round facts: per-MFMA wall ~125cyc in every config; only 2 waves/SIMD
// (124 VGPR + 64 acc AGPR); ~20us/residency-round overhead (r16 fit) with
// 33.5MB atomic RMW epilogue; barrier drains tax every lockstep schedule.
// All are artifacts of the 8-wave/split-K structure. This round:
//   - grid (256,2) = 512 blocks of 256 thr (4 waves, 2wm x 2wn, 32x32/wave)
//   - full K per block -> NO split-K -> NO atomics (plain stores, no zeroing)
//   - no shared af slab -> NO in-loop barriers (waves free-run, de-phase)
//   - acc 16 AGPR + ~100 VGPR -> 4 waves/SIMD, 2+ blocks/CU (LDS ~18KB)
// Per-CU MFMA invariant (8384). wt L2 re-read 537MB (ok). LDS floor ~31us.
// DO NOT add __launch_bounds__ min-waves: clamped VGPR -> 553MB spills (r16).
// K permutation: identity k'<128 (steps 0-1) | NICE [128,7936) (steps 2-123,
// uniform i, aligned j-octet) | RAGGED [7936,8384) (steps 124-130, gather).

constexpr int N_     = 128;
constexpr int S_     = 8256;
constexpr int BATCH_ = 16384;
constexpr int KTOT   = 8384;         // 131*64
constexpr int NKT    = 131;
constexpr size_t WT_BYTES = (size_t)KTOT * 128 * 2;
constexpr size_t PP_OFF   = WT_BYTES;                 // 2,146,304
constexpr size_t XH_OFF   = PP_OFF + 32768;           // pp needs 16.8KB; pad
// xh: 16384 cols x 128 rows fp16, pre-swizzled = 4 MB. ws total ~6.3 MB.

typedef __attribute__((ext_vector_type(8))) _Float16 half8;
typedef __attribute__((ext_vector_type(2))) _Float16 half2t;
typedef __attribute__((ext_vector_type(4))) float f32x4;

__device__ __forceinline__ ushort f2h(float f) {     // f32 -> fp16 bits (RNE)
    _Float16 h = (_Float16)f;
    ushort b; __builtin_memcpy(&b, &h, 2); return b;
}
__device__ __forceinline__ float h2f(ushort b) {
    _Float16 h; __builtin_memcpy(&h, &b, 2); return (float)h;
}
__device__ __forceinline__ half2t duph(ushort b) {   // {h, h} packed
    uint w = ((uint)b << 16) | (uint)b;
    half2t d; __builtin_memcpy(&d, &w, 4); return d;
}
__device__ __forceinline__ half8 mul_bc(half8 w, half2t d) {  // 4x v_pk_mul_f16
    union { half8 h; half2t p[4]; } u, r;
    u.h = w;
    #pragma unroll
    for (int q = 0; q < 4; ++q) r.p[q] = u.p[q] * d;
    return r.h;
}

// ---------- closed-form permutation helpers ----------
__device__ __forceinline__ int cumN(int i) {
    if (i <= 0) return 0;
    const int n = i - 1, t = n >> 3, r = n & 7;
    return 16 * i - (4 * t * (t + 1) + r * (t + 1));
}
__device__ __forceinline__ int offR(int i) {
    const int a = i >> 3, b = i & 7;
    const int p = b ? (8 * (b - 1) - (((b - 1) * b) >> 1)) : 0;
    return 28 * a + p;
}
__device__ __forceinline__ int triS(int i) { return i * (257 - i) / 2; }

// ---------- fused build: wt + pp + xh (no zero-out needed anymore) ----------
// W [0,524): wt fragments.  P {524}: pp table.  X [525,589): xh transpose+swz.
__global__ __launch_bounds__(256) void build_all(
    const float* __restrict__ x,
    const float* __restrict__ A, const float* __restrict__ B,
    ushort* __restrict__ pp, ushort* __restrict__ wt,
    ushort* __restrict__ xh)
{
    const int bid = blockIdx.x, t = threadIdx.x;
    if (bid < 524) {                              // ---- W: 1048 k-octets x 128 m ----
        const int idx = bid * 256 + t;            // [0, 134144)
        const int ko  = idx >> 7;                 // k-octet
        const int m   = idx & 127;
        const int kt = ko >> 3, kk = (ko >> 2) & 1, oct = ko & 3;
        const int lane = oct * 16 + (m & 15);
        const int e0 = kt * 8192 + kk * 4096 + (m >> 6) * 2048 +
                       ((m >> 4) & 3) * 512 + lane * 8;
        float v[8];
        if (ko < 16) {                            // identity: k = ko*8+el, A[m][k]
            const int i0 = ko * 8;
            #pragma unroll
            for (int el = 0; el < 8; ++el) v[el] = A[m * 128 + i0 + el];
        } else if (ko < 992) {                    // NICE: uniform i, aligned j-octet
            const int o = ko - 16;
            int i = 0;
            #pragma unroll
            for (int st = 64; st >= 1; st >>= 1) {
                const int c = i + st;
                if (c < 128 && cumN(c) <= o) i = c;
            }
            const int jb = ((i + 7) >> 3) + (o - cumN(i));
            const int s0 = triS(i) + jb * 8 - i;  // s = tri(i) + (j - i)
            const float* bp = B + (size_t)m * S_ + s0;
            #pragma unroll
            for (int el = 0; el < 8; ++el) v[el] = bp[el];
        } else {                                  // RAGGED: per-el gather
            const int kb = ko * 8 - 7936;
            #pragma unroll
            for (int el = 0; el < 8; ++el) {
                const int kloc = kb + el;
                int i = 0;
                #pragma unroll
                for (int st = 64; st >= 1; st >>= 1) {
                    const int c = i + st;
                    if (c < 128 && offR(c) <= kloc) i = c;
                }
                v[el] = B[(size_t)m * S_ + triS(i) + (kloc - offR(i))];
            }
        }
        ushort o8[8];
        #pragma unroll
        for (int el = 0; el < 8; ++el) o8[el] = f2h(v[el]);
        __builtin_memcpy(wt + e0, o8, 16);
    } else if (bid == 524) {                      // ---- P: pp table ----
        const int i = t;
        if (i < 128) {
            pp[i] = (ushort)(i | (0xFFu << 8));
            const int jb0 = (i + 7) >> 3;
            int kb = 128 + cumN(i) * 8;
            for (int jb = jb0; jb < 16; ++jb) {
                #pragma unroll
                for (int e = 0; e < 8; ++e)
                    pp[kb + e] = (ushort)(i | ((jb * 8 + e) << 8));
                kb += 8;
            }
            const int h = (8 - (i & 7)) & 7;
            const int rb = 7936 + offR(i);
            for (int e = 0; e < h; ++e)
                pp[rb + e] = (ushort)(i | ((i + e) << 8));
        }
    } else {                                      // ---- X: xh transpose+swz ----
        const int col = (bid - 525) * 256 + t;    // one column per thread
        ushort* xc = xh + (size_t)col * 128;
        const int cs = col & 15;
        #pragma unroll
        for (int ro = 0; ro < 16; ++ro) {
            uint ow[4];
            #pragma unroll
            for (int p = 0; p < 4; ++p) {
                const ushort u0 = f2h(x[(size_t)(ro * 8 + 2 * p) * BATCH_ + col]);
                const ushort u1 = f2h(x[(size_t)(ro * 8 + 2 * p + 1) * BATCH_ + col]);
                ow[p] = (uint)u0 | ((uint)u1 << 16);
            }
            __builtin_memcpy(xc + ((ro ^ cs) << 3), ow, 16);
        }
    }
}

// A-frags (4 = 2kk x 2mt): lane-linear b128 global loads (L2-resident wt).
__device__ __forceinline__ void load_af4(half8 af[4], const ushort* __restrict__ wt,
                                         int kt, int mb, int wm, int lane) {
    const ushort* ab = wt + ((size_t)kt << 13) + (mb << 11) + (wm << 10) +
                       (lane << 3);
    #pragma unroll
    for (int kk = 0; kk < 2; ++kk)
        #pragma unroll
        for (int mt = 0; mt < 2; ++mt)
            af[kk * 2 + mt] = *(const half8*)(ab + (kk << 12) + (mt << 9));
}

// ---------- phase 2: fused MFMA GEMM, 64x64 tile, full-K, barrier-free ----------
__global__ __launch_bounds__(256) void gemm_mfma(
    const ushort* __restrict__ xh,
    const ushort* __restrict__ wt,
    const ushort* __restrict__ pp,
    float* __restrict__ out)
{
    __shared__ ushort xt[64 * 128];    // 16 KB, 4-bit-octet swizzled
    __shared__ uint   ppc[NKT * 4];    // 2.1 KB packed pair words

    const int t    = threadIdx.x;
    const int b0   = blockIdx.x * 64;  // n-base
    const int mb   = blockIdx.y;       // m-half (0,1)
    const int lane = t & 63;
    const int w    = t >> 6;           // 4 waves
    const int wm   = w >> 1, wn = w & 1;   // wave covers 32 m x 32 n
    const int l16  = lane & 15, quad = lane >> 4;
    const int sw   = l16 << 3;             // 4-bit octet swizzle

    // ---- prologue: linear 16KB xt copy + ppc stage ----
    {
        const ushort* src = xh + (size_t)b0 * 128;
        #pragma unroll
        for (int i = 0; i < 4; ++i)
            *(half8*)(xt + i * 2048 + t * 8) =
                *(const half8*)(src + i * 2048 + t * 8);
    }
    for (int idx = t; idx < NKT * 4; idx += 256) {
        const int kt = idx >> 2, q = idx & 3;
        const uint a0 = *(const uint*)(pp + kt * 64 + q * 8);
        const uint a1 = *(const uint*)(pp + kt * 64 + 32 + q * 8);
        ppc[idx] = (a0 & 0xFFFFu) | ((a1 & 0xFFFFu) << 16);
    }
    __syncthreads();   // the only barrier in the kernel

    f32x4 acc[2][2];
    #pragma unroll
    for (int mt = 0; mt < 2; ++mt)
        #pragma unroll
        for (int nt = 0; nt < 2; ++nt)
            acc[mt][nt] = (f32x4){0.f, 0.f, 0.f, 0.f};

    const ushort* xbase = xt + (wn * 32 + l16) * 128;

    // ================= identity steps (kt = 0,1; all blocks) =================
    for (int kt = 0; kt < 2; ++kt) {
        half8 af[4];
        load_af4(af, wt, kt, mb, wm, lane);
        #pragma unroll
        for (int kk = 0; kk < 2; ++kk) {
            const int off = (kt * 64 + kk * 32 + quad * 8) ^ sw;
            #pragma unroll
            for (int nt = 0; nt < 2; ++nt) {
                const half8 bfr = *(const half8*)(xbase + nt * 2048 + off);
                #pragma unroll
                for (int mt = 0; mt < 2; ++mt)
                    acc[mt][nt] = __builtin_amdgcn_mfma_f32_16x16x32_f16(
                        af[kk * 2 + mt], bfr, acc[mt][nt], 0, 0, 0);
            }
        }
    }

    // ====== NICE steps (kt 2..123): barrier-free, waves free-run ======
    for (int kt = 2; kt < 124; ++kt) {
        half8 af[4];
        load_af4(af, wt, kt, mb, wm, lane);
        const uint prc = ppc[kt * 4 + quad];
        const int ia = (int)(prc & 0xFFu) ^ sw;
        const int ja = (int)((prc >> 8) & 0xFFu) ^ sw;
        const int ib = (int)((prc >> 16) & 0xFFu) ^ sw;
        const int jb = (int)(prc >> 24) ^ sw;

        ushort xi[2][2]; half8 wj[2][2];
        #pragma unroll
        for (int nt = 0; nt < 2; ++nt) {
            const ushort* xb = xbase + nt * 2048;
            xi[0][nt] = xb[ia];
            xi[1][nt] = xb[ib];
            wj[0][nt] = *(const half8*)(xb + ja);
            wj[1][nt] = *(const half8*)(xb + jb);
        }

        half8 bfr[2][2];
        #pragma unroll
        for (int kk = 0; kk < 2; ++kk)
            #pragma unroll
            for (int nt = 0; nt < 2; ++nt)
                bfr[kk][nt] = mul_bc(wj[kk][nt], duph(xi[kk][nt]));

        __builtin_amdgcn_s_setprio(1);
        #pragma unroll
        for (int kk = 0; kk < 2; ++kk)
            #pragma unroll
            for (int nt = 0; nt < 2; ++nt)
                #pragma unroll
                for (int mt = 0; mt < 2; ++mt)
                    acc[mt][nt] = __builtin_amdgcn_mfma_f32_16x16x32_f16(
                        af[kk * 2 + mt], bfr[kk][nt], acc[mt][nt], 0, 0, 0);
        __builtin_amdgcn_s_setprio(0);
    }

    // ================= ragged steps (kt = 124..130; all blocks) =================
    for (int kt = 124; kt < NKT; ++kt) {
        half8 af[4];
        load_af4(af, wt, kt, mb, wm, lane);
        #pragma unroll
        for (int kk = 0; kk < 2; ++kk) {
            const int k0 = kt * 64 + kk * 32 + quad * 8;
            const uint4 pk = *(const uint4*)(pp + k0);
            const uint pr4[4] = {pk.x, pk.y, pk.z, pk.w};
            #pragma unroll
            for (int nt = 0; nt < 2; ++nt) {
                const ushort* xb = xbase + nt * 2048;
                float prods[8];
                #pragma unroll
                for (int e = 0; e < 8; ++e) {
                    const uint ent = (pr4[e >> 1] >> ((e & 1) * 16)) & 0xFFFFu;
                    prods[e] = h2f(xb[(int)(ent & 0xFFu) ^ sw]) *
                               h2f(xb[(int)(ent >> 8) ^ sw]);
                }
                union { half8 h; uint wdw[4]; } bb;
                #pragma unroll
                for (int p = 0; p < 4; ++p) {
                    const auto pk2 = __builtin_amdgcn_cvt_pkrtz(
                        prods[2 * p], prods[2 * p + 1]);
                    __builtin_memcpy(&bb.wdw[p], &pk2, 4);
                }
                const half8 bfr = bb.h;
                #pragma unroll
                for (int mt = 0; mt < 2; ++mt)
                    acc[mt][nt] = __builtin_amdgcn_mfma_f32_16x16x32_f16(
                        af[kk * 2 + mt], bfr, acc[mt][nt], 0, 0, 0);
            }
        }
    }

    // ---- epilogue: PLAIN stores (each tile uniquely owned; no atomics) ----
    #pragma unroll
    for (int mt = 0; mt < 2; ++mt) {
        #pragma unroll
        for (int nt = 0; nt < 2; ++nt) {
            const int mbase = mb * 64 + wm * 32 + mt * 16 + quad * 4;
            const size_t col = (size_t)b0 + wn * 32 + nt * 16 + l16;
            #pragma unroll
            for (int r = 0; r < 4; ++r)
                out[(size_t)(mbase + r) * BATCH_ + col] = acc[mt][nt][r];
        }
    }
}

extern "C" void kernel_launch(void* const* d_in, const int* in_sizes, int n_in,
                              void* d_out, int out_size, void* d_ws, size_t ws_size,
                              hipStream_t stream) {
    const float* x = (const float*)d_in[0];   // [128, 16384]
    const float* A = (const float*)d_in[1];   // [128, 128]
    const float* B = (const float*)d_in[2];   // [128, 8256]
    float* out = (float*)d_out;               // [128, 16384]

    ushort* wt = (ushort*)d_ws;
    ushort* pp = (ushort*)((char*)d_ws + PP_OFF);
    ushort* xh = (ushort*)((char*)d_ws + XH_OFF);

    build_all<<<589, 256, 0, stream>>>(x, A, B, pp, wt, xh);
    gemm_mfma<<<dim3(BATCH_ / 64, 2), 256, 0, stream>>>(xh, wt, pp, out);
}

// Round 12
// 129.175 us; speedup vs baseline: 1.0129x; 1.0129x over previous
//
#include <hip/hip_runtime.h>

// out[128,16384] = [A|B](128x8384) @ [x; x2](8384x16384), fp16 MFMA.
// Round 21 = the 4-waves/SIMD point of the constraint web.
// Measured laws (r9..r20): per-CU MFMA fixed 8448; B-gen VALU / CU ~ 1/Wm;
// af L2 traffic ~ 1/Wn (L1 absorbs intra-block redundancy); occupancy needs
// arch+acc <= 128 unified regs AND waves = (128/Wm)(16384/Wn)s >= 4096 AND
// LDS*blocks <= 160KB. r17 (64x64,s4): 2 waves/SIMD, 188 regs. r20 (32x32):
// grid-capped 2/SIMD, 2x VALU. Unique untested point: Wm=64 Wn=32 s=4,
// 4-wave 256-thr blocks, tile 64m x 128n, xt 32KB -> 4096 waves (4/SIMD),
// acc 32, arch ~90, 4 blocks/CU. Free-running waves (no in-loop barriers),
// per-step global af (L1-served), split-K atomics back (32.8MB, cheap).
// DO NOT add __launch_bounds__ min-waves: clamped VGPR -> 553MB spills (r16).
// K permutation: identity k'<128 (steps 0-1) | NICE [128,7936) (steps 2-123,
// uniform i, aligned j-octet) | RAGGED [7936,8384) (steps 124-130, gather).

constexpr int N_     = 128;
constexpr int S_     = 8256;
constexpr int BATCH_ = 16384;
constexpr int KTOT   = 8384;         // 131*64
constexpr int NKT    = 131;
constexpr size_t WT_BYTES = (size_t)KTOT * 128 * 2;
constexpr size_t PP_OFF   = WT_BYTES;                 // 2,146,304
constexpr size_t XH_OFF   = PP_OFF + 32768;           // pp needs 16.8KB; pad
// xh: 16384 cols x 128 rows fp16, pre-swizzled = 4 MB. ws total ~6.3 MB.

typedef __attribute__((ext_vector_type(8))) _Float16 half8;
typedef __attribute__((ext_vector_type(2))) _Float16 half2t;
typedef __attribute__((ext_vector_type(4))) float f32x4;

__device__ __forceinline__ ushort f2h(float f) {     // f32 -> fp16 bits (RNE)
    _Float16 h = (_Float16)f;
    ushort b; __builtin_memcpy(&b, &h, 2); return b;
}
__device__ __forceinline__ float h2f(ushort b) {
    _Float16 h; __builtin_memcpy(&h, &b, 2); return (float)h;
}
__device__ __forceinline__ half2t duph(ushort b) {   // {h, h} packed
    uint w = ((uint)b << 16) | (uint)b;
    half2t d; __builtin_memcpy(&d, &w, 4); return d;
}
__device__ __forceinline__ half8 mul_bc(half8 w, half2t d) {  // 4x v_pk_mul_f16
    union { half8 h; half2t p[4]; } u, r;
    u.h = w;
    #pragma unroll
    for (int q = 0; q < 4; ++q) r.p[q] = u.p[q] * d;
    return r.h;
}

// ---------- closed-form permutation helpers ----------
__device__ __forceinline__ int cumN(int i) {
    if (i <= 0) return 0;
    const int n = i - 1, t = n >> 3, r = n & 7;
    return 16 * i - (4 * t * (t + 1) + r * (t + 1));
}
__device__ __forceinline__ int offR(int i) {
    const int a = i >> 3, b = i & 7;
    const int p = b ? (8 * (b - 1) - (((b - 1) * b) >> 1)) : 0;
    return 28 * a + p;
}
__device__ __forceinline__ int triS(int i) { return i * (257 - i) / 2; }

// ---------- fused build: wt + zero-out + pp + xh (no internal deps) ----------
// W [0,524): wt fragments.  Z [524,780): zero out.  P {780}: pp table.
// X [781,845): xh[col][r ^ ((col&15)<<3)] = fp16 x[r][col]  (transpose+swz).
__global__ __launch_bounds__(256) void build_all(
    const float* __restrict__ x,
    const float* __restrict__ A, const float* __restrict__ B,
    ushort* __restrict__ pp, ushort* __restrict__ wt,
    ushort* __restrict__ xh, float* __restrict__ out)
{
    const int bid = blockIdx.x, t = threadIdx.x;
    if (bid < 524) {                              // ---- W: 1048 k-octets x 128 m ----
        const int idx = bid * 256 + t;            // [0, 134144)
        const int ko  = idx >> 7;                 // k-octet
        const int m   = idx & 127;
        const int kt = ko >> 3, kk = (ko >> 2) & 1, oct = ko & 3;
        const int lane = oct * 16 + (m & 15);
        const int e0 = kt * 8192 + kk * 4096 + (m >> 6) * 2048 +
                       ((m >> 4) & 3) * 512 + lane * 8;
        float v[8];
        if (ko < 16) {                            // identity: k = ko*8+el, A[m][k]
            const int i0 = ko * 8;
            #pragma unroll
            for (int el = 0; el < 8; ++el) v[el] = A[m * 128 + i0 + el];
        } else if (ko < 992) {                    // NICE: uniform i, aligned j-octet
            const int o = ko - 16;
            int i = 0;
            #pragma unroll
            for (int st = 64; st >= 1; st >>= 1) {
                const int c = i + st;
                if (c < 128 && cumN(c) <= o) i = c;
            }
            const int jb = ((i + 7) >> 3) + (o - cumN(i));
            const int s0 = triS(i) + jb * 8 - i;  // s = tri(i) + (j - i)
            const float* bp = B + (size_t)m * S_ + s0;
            #pragma unroll
            for (int el = 0; el < 8; ++el) v[el] = bp[el];
        } else {                                  // RAGGED: per-el gather
            const int kb = ko * 8 - 7936;
            #pragma unroll
            for (int el = 0; el < 8; ++el) {
                const int kloc = kb + el;
                int i = 0;
                #pragma unroll
                for (int st = 64; st >= 1; st >>= 1) {
                    const int c = i + st;
                    if (c < 128 && offR(c) <= kloc) i = c;
                }
                v[el] = B[(size_t)m * S_ + triS(i) + (kloc - offR(i))];
            }
        }
        ushort o8[8];
        #pragma unroll
        for (int el = 0; el < 8; ++el) o8[el] = f2h(v[el]);
        __builtin_memcpy(wt + e0, o8, 16);
    } else if (bid < 780) {                       // ---- Z: zero out ----
        const int zb = bid - 524;
        f32x4* o4 = (f32x4*)out;
        #pragma unroll
        for (int c = 0; c < 4; ++c)
            o4[(size_t)zb * 2048 + c * 512 + t] = (f32x4){0.f, 0.f, 0.f, 0.f};
    } else if (bid == 780) {                      // ---- P: pp table ----
        const int i = t;
        if (i < 128) {
            pp[i] = (ushort)(i | (0xFFu << 8));
            const int jb0 = (i + 7) >> 3;
            int kb = 128 + cumN(i) * 8;
            for (int jb = jb0; jb < 16; ++jb) {
                #pragma unroll
                for (int e = 0; e < 8; ++e)
                    pp[kb + e] = (ushort)(i | ((jb * 8 + e) << 8));
                kb += 8;
            }
            const int h = (8 - (i & 7)) & 7;
            const int rb = 7936 + offR(i);
            for (int e = 0; e < h; ++e)
                pp[rb + e] = (ushort)(i | ((i + e) << 8));
        }
    } else {                                      // ---- X: xh transpose+swz ----
        const int col = (bid - 781) * 256 + t;    // one column per thread
        ushort* xc = xh + (size_t)col * 128;
        const int cs = col & 15;
        #pragma unroll
        for (int ro = 0; ro < 16; ++ro) {
            uint ow[4];
            #pragma unroll
            for (int p = 0; p < 4; ++p) {
                const ushort u0 = f2h(x[(size_t)(ro * 8 + 2 * p) * BATCH_ + col]);
                const ushort u1 = f2h(x[(size_t)(ro * 8 + 2 * p + 1) * BATCH_ + col]);
                ow[p] = (uint)u0 | ((uint)u1 << 16);
            }
            __builtin_memcpy(xc + ((ro ^ cs) << 3), ow, 16);
        }
    }
}

// A-frags (8 = 2kk x 4mt) for the wave's 64-m half: lane-linear b128 global
// loads; all 4 waves of a block read the same 8KB -> L1-served redundancy.
__device__ __forceinline__ void load_af8(half8 af[8], const ushort* __restrict__ wt,
                                         int kt, int mb, int lane) {
    const ushort* ab = wt + ((size_t)kt << 13) + (mb << 11) + (lane << 3);
    #pragma unroll
    for (int kk = 0; kk < 2; ++kk)
        #pragma unroll
        for (int mt = 0; mt < 4; ++mt)
            af[kk * 4 + mt] = *(const half8*)(ab + (kk << 12) + (mt << 9));
}

// ---------- phase 2: fused MFMA GEMM, 64m x 128n tile, split-K x4 ----------
// 256 thr = 4 waves, wave w = n-subtile w (64m x 32n each), free-running.
__global__ __launch_bounds__(256) void gemm_mfma(
    const ushort* __restrict__ xh,
    const ushort* __restrict__ wt,
    const ushort* __restrict__ pp,
    float* __restrict__ out)
{
    __shared__ ushort xt[128 * 128];   // 32 KB, 4-bit-octet swizzled
    __shared__ uint   ppc[NKT * 4];    // 2.1 KB packed pair words

    const int t    = threadIdx.x;
    const int b0   = blockIdx.x * 128;       // n-base (128 cols)
    const int mb   = blockIdx.y & 1;         // m-half
    const int sp   = blockIdx.y >> 1;        // split-K 0..3
    const int kt0  = sp * 33;
    const int kt1  = (sp == 3) ? NKT : kt0 + 33;
    const int lane = t & 63;
    const int wn   = t >> 6;                 // wave = n-subtile 0..3
    const int l16  = lane & 15, quad = lane >> 4;
    const int sw   = l16 << 3;               // 4-bit octet swizzle

    const int s_ni = (kt0 > 2) ? kt0 : 2;
    const int e_ni = (kt1 < 124) ? kt1 : 124;

    // ---- prologue: linear 32KB xt copy + ppc stage ----
    {
        const ushort* src = xh + (size_t)b0 * 128;
        #pragma unroll
        for (int i = 0; i < 8; ++i)
            *(half8*)(xt + i * 2048 + t * 8) =
                *(const half8*)(src + i * 2048 + t * 8);
    }
    for (int idx = t; idx < NKT * 4; idx += 256) {
        const int kt = idx >> 2, q = idx & 3;
        const uint a0 = *(const uint*)(pp + kt * 64 + q * 8);
        const uint a1 = *(const uint*)(pp + kt * 64 + 32 + q * 8);
        ppc[idx] = (a0 & 0xFFFFu) | ((a1 & 0xFFFFu) << 16);
    }
    __syncthreads();   // the only barrier

    f32x4 acc[4][2];
    #pragma unroll
    for (int mt = 0; mt < 4; ++mt)
        #pragma unroll
        for (int nt = 0; nt < 2; ++nt)
            acc[mt][nt] = (f32x4){0.f, 0.f, 0.f, 0.f};

    const ushort* xbase = xt + (wn * 32 + l16) * 128;

    // ================= identity steps (kt = 0,1; sp==0 only) =================
    if (sp == 0) {
        for (int kt = 0; kt < 2; ++kt) {
            half8 af[8];
            load_af8(af, wt, kt, mb, lane);
            #pragma unroll
            for (int kk = 0; kk < 2; ++kk) {
                const int off = (kt * 64 + kk * 32 + quad * 8) ^ sw;
                #pragma unroll
                for (int nt = 0; nt < 2; ++nt) {
                    const half8 bfr = *(const half8*)(xbase + nt * 2048 + off);
                    #pragma unroll
                    for (int mt = 0; mt < 4; ++mt)
                        acc[mt][nt] = __builtin_amdgcn_mfma_f32_16x16x32_f16(
                            af[kk * 4 + mt], bfr, acc[mt][nt], 0, 0, 0);
                }
            }
        }
    }

    // ====== NICE steps: free-running, straight-line (register-lean) ======
    for (int kt = s_ni; kt < e_ni; ++kt) {
        half8 af[8];
        load_af8(af, wt, kt, mb, lane);
        const uint prc = ppc[kt * 4 + quad];
        const int ia = (int)(prc & 0xFFu) ^ sw;
        const int ja = (int)((prc >> 8) & 0xFFu) ^ sw;
        const int ib = (int)((prc >> 16) & 0xFFu) ^ sw;
        const int jb = (int)(prc >> 24) ^ sw;

        ushort xi[2][2]; half8 wj[2][2];
        #pragma unroll
        for (int nt = 0; nt < 2; ++nt) {
            const ushort* xb = xbase + nt * 2048;
            xi[0][nt] = xb[ia];
            xi[1][nt] = xb[ib];
            wj[0][nt] = *(const half8*)(xb + ja);
            wj[1][nt] = *(const half8*)(xb + jb);
        }

        half8 bfr[2][2];
        #pragma unroll
        for (int kk = 0; kk < 2; ++kk)
            #pragma unroll
            for (int nt = 0; nt < 2; ++nt)
                bfr[kk][nt] = mul_bc(wj[kk][nt], duph(xi[kk][nt]));

        __builtin_amdgcn_s_setprio(1);
        #pragma unroll
        for (int kk = 0; kk < 2; ++kk)
            #pragma unroll
            for (int nt = 0; nt < 2; ++nt)
                #pragma unroll
                for (int mt = 0; mt < 4; ++mt)
                    acc[mt][nt] = __builtin_amdgcn_mfma_f32_16x16x32_f16(
                        af[kk * 4 + mt], bfr[kk][nt], acc[mt][nt], 0, 0, 0);
        __builtin_amdgcn_s_setprio(0);
    }

    // ================= ragged steps (kt = 124..130; sp==3 only) =================
    if (sp == 3) {
        for (int kt = 124; kt < NKT; ++kt) {
            half8 af[8];
            load_af8(af, wt, kt, mb, lane);
            #pragma unroll
            for (int kk = 0; kk < 2; ++kk) {
                const int k0 = kt * 64 + kk * 32 + quad * 8;
                const uint4 pk = *(const uint4*)(pp + k0);
                const uint pr4[4] = {pk.x, pk.y, pk.z, pk.w};
                #pragma unroll
                for (int nt = 0; nt < 2; ++nt) {
                    const ushort* xb = xbase + nt * 2048;
                    float prods[8];
                    #pragma unroll
                    for (int e = 0; e < 8; ++e) {
                        const uint ent = (pr4[e >> 1] >> ((e & 1) * 16)) & 0xFFFFu;
                        prods[e] = h2f(xb[(int)(ent & 0xFFu) ^ sw]) *
                                   h2f(xb[(int)(ent >> 8) ^ sw]);
                    }
                    union { half8 h; uint wdw[4]; } bb;
                    #pragma unroll
                    for (int p = 0; p < 4; ++p) {
                        const auto pk2 = __builtin_amdgcn_cvt_pkrtz(
                            prods[2 * p], prods[2 * p + 1]);
                        __builtin_memcpy(&bb.wdw[p], &pk2, 4);
                    }
                    const half8 bfr = bb.h;
                    #pragma unroll
                    for (int mt = 0; mt < 4; ++mt)
                        acc[mt][nt] = __builtin_amdgcn_mfma_f32_16x16x32_f16(
                            af[kk * 4 + mt], bfr, acc[mt][nt], 0, 0, 0);
                }
            }
        }
    }

    // ---- epilogue: atomic accumulate (C/D: col=lane&15, row=quad*4+reg) ----
    #pragma unroll
    for (int mt = 0; mt < 4; ++mt) {
        #pragma unroll
        for (int nt = 0; nt < 2; ++nt) {
            const int mbase = mb * 64 + mt * 16 + quad * 4;
            const size_t col = (size_t)b0 + wn * 32 + nt * 16 + l16;
            #pragma unroll
            for (int r = 0; r < 4; ++r)
                unsafeAtomicAdd(&out[(size_t)(mbase + r) * BATCH_ + col],
                                acc[mt][nt][r]);
        }
    }
}

extern "C" void kernel_launch(void* const* d_in, const int* in_sizes, int n_in,
                              void* d_out, int out_size, void* d_ws, size_t ws_size,
                              hipStream_t stream) {
    const float* x = (const float*)d_in[0];   // [128, 16384]
    const float* A = (const float*)d_in[1];   // [128, 128]
    const float* B = (const float*)d_in[2];   // [128, 8256]
    float* out = (float*)d_out;               // [128, 16384]

    ushort* wt = (ushort*)d_ws;
    ushort* pp = (ushort*)((char*)d_ws + PP_OFF);
    ushort* xh = (ushort*)((char*)d_ws + XH_OFF);

    build_all<<<845, 256, 0, stream>>>(x, A, B, pp, wt, xh, out);
    gemm_mfma<<<dim3(BATCH_ / 128, 8), 256, 0, stream>>>(xh, wt, pp, out);
}

// Round 13
// 121.258 us; speedup vs baseline: 1.0790x; 1.0653x over previous
//
#include <hip/hip_runtime.h>

// out[128,16384] = [A|B](128x8384) @ [x; x2](8384x16384), fp16 MFMA.
// Round 22 = EXACT r17 kernel (best, 58.4us gemm) + ONE change:
//   __launch_bounds__(512, 2) on gemm_mfma.
// Theory (from 12 rounds of invariance): wall ~= SUM of pipe times, zero
// overlap, despite all loads source-prefetched a full step (~2400cyc) ahead.
// VGPR_Count pinned at exactly 124 across r13-r19 (5 different structures):
// the allocator targets the 128-reg/4-wave cliff, but real occupancy is
// 124+64acc=188 unified -> 2 waves/SIMD regardless. To stay <=128 it SINKS
// every prefetch to just-before-use -> effective pipeline depth 0 -> pipes
// serialize. min-waves=2 states the true occupancy target and raises the
// unified cap to ~256, freeing the scheduler to keep prefetches live.
// This is the INVERSE of r15's (512,4) disaster: that LOWERED the cap below
// need (124->64, spills); 2 == current reality, cannot reduce occupancy.
// Test: VGPR should jump 124 -> 150-230. If it stays 124, theory is dead.
// K permutation: identity k'<128 (steps 0-1) | NICE [128,7936) (steps 2-123,
// uniform i, aligned j-octet) | RAGGED [7936,8384) (steps 124-130, gather).

constexpr int N_     = 128;
constexpr int S_     = 8256;
constexpr int BATCH_ = 16384;
constexpr int KTOT   = 8384;         // 131*64
constexpr int NKT    = 131;
constexpr size_t WT_BYTES = (size_t)KTOT * 128 * 2;
constexpr size_t PP_OFF   = WT_BYTES;                 // 2,146,304
constexpr size_t XH_OFF   = PP_OFF + 32768;           // pp needs 16.8KB; pad
// xh: 16384 cols x 128 rows fp16, pre-swizzled = 4 MB. ws total ~6.3 MB.

typedef __attribute__((ext_vector_type(8))) _Float16 half8;
typedef __attribute__((ext_vector_type(2))) _Float16 half2t;
typedef __attribute__((ext_vector_type(4))) float f32x4;

__device__ __forceinline__ ushort f2h(float f) {     // f32 -> fp16 bits (RNE)
    _Float16 h = (_Float16)f;
    ushort b; __builtin_memcpy(&b, &h, 2); return b;
}
__device__ __forceinline__ float h2f(ushort b) {
    _Float16 h; __builtin_memcpy(&h, &b, 2); return (float)h;
}
__device__ __forceinline__ half2t duph(ushort b) {   // {h, h} packed
    uint w = ((uint)b << 16) | (uint)b;
    half2t d; __builtin_memcpy(&d, &w, 4); return d;
}
__device__ __forceinline__ half8 mul_bc(half8 w, half2t d) {  // 4x v_pk_mul_f16
    union { half8 h; half2t p[4]; } u, r;
    u.h = w;
    #pragma unroll
    for (int q = 0; q < 4; ++q) r.p[q] = u.p[q] * d;
    return r.h;
}

// ---------- closed-form permutation helpers ----------
__device__ __forceinline__ int cumN(int i) {
    if (i <= 0) return 0;
    const int n = i - 1, t = n >> 3, r = n & 7;
    return 16 * i - (4 * t * (t + 1) + r * (t + 1));
}
__device__ __forceinline__ int offR(int i) {
    const int a = i >> 3, b = i & 7;
    const int p = b ? (8 * (b - 1) - (((b - 1) * b) >> 1)) : 0;
    return 28 * a + p;
}
__device__ __forceinline__ int triS(int i) { return i * (257 - i) / 2; }

// ---------- fused build: wt + zero-out + pp + xh (no internal deps) ----------
// W [0,524): wt fragments.  Z [524,780): zero out.  P {780}: pp table.
// X [781,845): xh[col][r ^ ((col&15)<<3)] = fp16 x[r][col]  (transpose+swz).
__global__ __launch_bounds__(256) void build_all(
    const float* __restrict__ x,
    const float* __restrict__ A, const float* __restrict__ B,
    ushort* __restrict__ pp, ushort* __restrict__ wt,
    ushort* __restrict__ xh, float* __restrict__ out)
{
    const int bid = blockIdx.x, t = threadIdx.x;
    if (bid < 524) {                              // ---- W: 1048 k-octets x 128 m ----
        const int idx = bid * 256 + t;            // [0, 134144)
        const int ko  = idx >> 7;                 // k-octet
        const int m   = idx & 127;
        const int kt = ko >> 3, kk = (ko >> 2) & 1, oct = ko & 3;
        const int lane = oct * 16 + (m & 15);
        const int e0 = kt * 8192 + kk * 4096 + (m >> 6) * 2048 +
                       ((m >> 4) & 3) * 512 + lane * 8;
        float v[8];
        if (ko < 16) {                            // identity: k = ko*8+el, A[m][k]
            const int i0 = ko * 8;
            #pragma unroll
            for (int el = 0; el < 8; ++el) v[el] = A[m * 128 + i0 + el];
        } else if (ko < 992) {                    // NICE: uniform i, aligned j-octet
            const int o = ko - 16;
            int i = 0;
            #pragma unroll
            for (int st = 64; st >= 1; st >>= 1) {
                const int c = i + st;
                if (c < 128 && cumN(c) <= o) i = c;
            }
            const int jb = ((i + 7) >> 3) + (o - cumN(i));
            const int s0 = triS(i) + jb * 8 - i;  // s = tri(i) + (j - i)
            const float* bp = B + (size_t)m * S_ + s0;
            #pragma unroll
            for (int el = 0; el < 8; ++el) v[el] = bp[el];
        } else {                                  // RAGGED: per-el gather
            const int kb = ko * 8 - 7936;
            #pragma unroll
            for (int el = 0; el < 8; ++el) {
                const int kloc = kb + el;
                int i = 0;
                #pragma unroll
                for (int st = 64; st >= 1; st >>= 1) {
                    const int c = i + st;
                    if (c < 128 && offR(c) <= kloc) i = c;
                }
                v[el] = B[(size_t)m * S_ + triS(i) + (kloc - offR(i))];
            }
        }
        ushort o8[8];
        #pragma unroll
        for (int el = 0; el < 8; ++el) o8[el] = f2h(v[el]);
        __builtin_memcpy(wt + e0, o8, 16);
    } else if (bid < 780) {                       // ---- Z: zero out ----
        const int zb = bid - 524;
        f32x4* o4 = (f32x4*)out;
        #pragma unroll
        for (int c = 0; c < 4; ++c)
            o4[(size_t)zb * 2048 + c * 512 + t] = (f32x4){0.f, 0.f, 0.f, 0.f};
    } else if (bid == 780) {                      // ---- P: pp table ----
        const int i = t;
        if (i < 128) {
            pp[i] = (ushort)(i | (0xFFu << 8));
            const int jb0 = (i + 7) >> 3;
            int kb = 128 + cumN(i) * 8;
            for (int jb = jb0; jb < 16; ++jb) {
                #pragma unroll
                for (int e = 0; e < 8; ++e)
                    pp[kb + e] = (ushort)(i | ((jb * 8 + e) << 8));
                kb += 8;
            }
            const int h = (8 - (i & 7)) & 7;
            const int rb = 7936 + offR(i);
            for (int e = 0; e < h; ++e)
                pp[rb + e] = (ushort)(i | ((i + e) << 8));
        }
    } else {                                      // ---- X: xh transpose+swz ----
        const int col = (bid - 781) * 256 + t;    // one column per thread
        ushort* xc = xh + (size_t)col * 128;
        const int cs = col & 15;
        #pragma unroll
        for (int ro = 0; ro < 16; ++ro) {
            uint ow[4];
            #pragma unroll
            for (int p = 0; p < 4; ++p) {
                const ushort u0 = f2h(x[(size_t)(ro * 8 + 2 * p) * BATCH_ + col]);
                const ushort u1 = f2h(x[(size_t)(ro * 8 + 2 * p + 1) * BATCH_ + col]);
                ow[p] = (uint)u0 | ((uint)u1 << 16);
            }
            __builtin_memcpy(xc + ((ro ^ cs) << 3), ow, 16);
        }
    }
}

// A-frags for step kt: 8 lane-linear b128 loads (coalesced layout).
__device__ __forceinline__ void load_af(half8 af[8], const ushort* __restrict__ wt,
                                        int kt, int wm, int lane) {
    const ushort* ab = wt + ((size_t)kt << 13) + (wm << 11) + (lane << 3);
    #pragma unroll
    for (int kk = 0; kk < 2; ++kk)
        #pragma unroll
        for (int mt = 0; mt < 4; ++mt)
            af[kk * 4 + mt] = *(const half8*)(ab + (kk << 12) + (mt << 9));
}

// Issue the LDS reads for one NICE step (8 scalar + 8 b128, all independent).
__device__ __forceinline__ void read_bin(ushort xi[2][4], half8 wj[2][4],
                                         uint w0, uint w1,
                                         const ushort* __restrict__ xbase,
                                         int sw) {
    const int ia = (int)(w0 & 0xFFu) ^ sw, ja = (int)((w0 >> 8) & 0xFFu) ^ sw;
    const int ib = (int)(w1 & 0xFFu) ^ sw, jb = (int)((w1 >> 8) & 0xFFu) ^ sw;
    #pragma unroll
    for (int nt = 0; nt < 4; ++nt) {
        const ushort* xb = xbase + nt * 2048;
        xi[0][nt] = xb[ia];
        xi[1][nt] = xb[ib];
        wj[0][nt] = *(const half8*)(xb + ja);
        wj[1][nt] = *(const half8*)(xb + jb);
    }
}

// Pack B-frags (inputs loaded a full iteration ago) + 32 MFMA under setprio.
__device__ __forceinline__ void mfma_step(f32x4 acc[4][4], const half8 af[8],
                                          const ushort xi[2][4],
                                          const half8 wj[2][4]) {
    half8 bfr[2][4];
    #pragma unroll
    for (int kk = 0; kk < 2; ++kk)
        #pragma unroll
        for (int nt = 0; nt < 4; ++nt)
            bfr[kk][nt] = mul_bc(wj[kk][nt], duph(xi[kk][nt]));
    __builtin_amdgcn_s_setprio(1);
    #pragma unroll
    for (int kk = 0; kk < 2; ++kk)
        #pragma unroll
        for (int nt = 0; nt < 4; ++nt)
            #pragma unroll
            for (int mt = 0; mt < 4; ++mt)
                acc[mt][nt] = __builtin_amdgcn_mfma_f32_16x16x32_f16(
                    af[kk * 4 + mt], bfr[kk][nt], acc[mt][nt], 0, 0, 0);
    __builtin_amdgcn_s_setprio(0);
}

// ---------- phase 2: fused MFMA GEMM, 128x256 tile, split-K x4 ----------
// (512, 2): truthful min-occupancy -> raises unified VGPR cap to ~256 so the
// scheduler stops sinking prefetches to stay under the (irrelevant) 128 cliff.
__global__ __launch_bounds__(512, 2) void gemm_mfma(
    const ushort* __restrict__ xh,
    const ushort* __restrict__ wt,
    const ushort* __restrict__ pp,
    float* __restrict__ out)
{
    __shared__ ushort xt[256 * 128];   // exactly 64 KB, 4-bit-octet swizzled

    const int t    = threadIdx.x;
    const int b0   = blockIdx.x * 256;
    const int sp   = blockIdx.y;       // 0..3
    const int kt0  = sp * 33;          // 0,33,66,99
    const int kt1  = (sp == 3) ? NKT : kt0 + 33;
    const int lane = t & 63;
    const int w    = t >> 6;
    const int wm   = w >> 2, wn = w & 3;   // wave covers 64 m x 64 n
    const int l16  = lane & 15, quad = lane >> 4;
    const int sw   = l16 << 3;             // 4-bit octet swizzle

    // ---- stage xt: pure linear 64KB copy (xh is pre-swizzled fp16) ----
    {
        const ushort* src = xh + (size_t)b0 * 128;
        #pragma unroll
        for (int i = 0; i < 8; ++i)
            *(half8*)(xt + i * 4096 + t * 8) =
                *(const half8*)(src + i * 4096 + t * 8);
    }
    __syncthreads();

    f32x4 acc[4][4];
    #pragma unroll
    for (int mt = 0; mt < 4; ++mt)
        #pragma unroll
        for (int nt = 0; nt < 4; ++nt)
            acc[mt][nt] = (f32x4){0.f, 0.f, 0.f, 0.f};

    const ushort* xbase = xt + (wn * 64 + l16) * 128;

    // ================= identity steps (kt = 0,1; sp==0 only) =================
    if (sp == 0) {
        for (int kt = 0; kt < 2; ++kt) {
            half8 af[8];
            load_af(af, wt, kt, wm, lane);
            #pragma unroll
            for (int kk = 0; kk < 2; ++kk) {
                const int off = (kt * 64 + kk * 32 + quad * 8) ^ sw;
                #pragma unroll
                for (int nt = 0; nt < 4; ++nt) {
                    const half8 bfr = *(const half8*)(xbase + nt * 2048 + off);
                    #pragma unroll
                    for (int mt = 0; mt < 4; ++mt)
                        acc[mt][nt] = __builtin_amdgcn_mfma_f32_16x16x32_f16(
                            af[kk * 4 + mt], bfr, acc[mt][nt], 0, 0, 0);
                }
            }
        }
    }

    // ====== NICE steps: depth-2 pipeline, per-wave rotation, setprio ======
    {
        const int s_ni = (kt0 > 2) ? kt0 : 2;
        const int e_ni = (kt1 < 124) ? kt1 : 124;
        const int len  = e_ni - s_ni;
        if (len > 0) {
            int kt  = s_ni + ((w * len) >> 3);
            int ktn = (kt + 1 < e_ni) ? kt + 1 : s_ni;

            half8  afA[8], afB[8];
            ushort xiA[2][4], xiB[2][4];
            half8  wjA[2][4], wjB[2][4];

            const uint c0 = *(const uint*)(pp + kt * 64 + quad * 8);
            const uint c1 = *(const uint*)(pp + kt * 64 + 32 + quad * 8);
            load_af(afA, wt, kt, wm, lane);
            uint n0 = *(const uint*)(pp + ktn * 64 + quad * 8);
            uint n1 = *(const uint*)(pp + ktn * 64 + 32 + quad * 8);
            read_bin(xiA, wjA, c0, c1, xbase, sw);

            int rem = len;
            while (true) {
                {   // compute kt from A-buffers; prefetch ktn into B-buffers
                    const int kt2 = (ktn + 1 < e_ni) ? ktn + 1 : s_ni;
                    const uint m0 = *(const uint*)(pp + kt2 * 64 + quad * 8);
                    const uint m1 = *(const uint*)(pp + kt2 * 64 + 32 + quad * 8);
                    load_af(afB, wt, ktn, wm, lane);
                    read_bin(xiB, wjB, n0, n1, xbase, sw);
                    mfma_step(acc, afA, xiA, wjA);
                    n0 = m0; n1 = m1; ktn = kt2;
                    if (--rem == 0) break;
                }
                {   // swap roles
                    const int kt2 = (ktn + 1 < e_ni) ? ktn + 1 : s_ni;
                    const uint m0 = *(const uint*)(pp + kt2 * 64 + quad * 8);
                    const uint m1 = *(const uint*)(pp + kt2 * 64 + 32 + quad * 8);
                    load_af(afA, wt, ktn, wm, lane);
                    read_bin(xiA, wjA, n0, n1, xbase, sw);
                    mfma_step(acc, afB, xiB, wjB);
                    n0 = m0; n1 = m1; ktn = kt2;
                    if (--rem == 0) break;
                }
            }
        }
    }

    // ================= ragged steps (kt = 124..130; sp==3 only) =================
    if (sp == 3) {
        for (int kt = 124; kt < NKT; ++kt) {
            half8 af[8];
            load_af(af, wt, kt, wm, lane);
            #pragma unroll
            for (int kk = 0; kk < 2; ++kk) {
                const int k0 = kt * 64 + kk * 32 + quad * 8;
                const uint4 pk = *(const uint4*)(pp + k0);
                const uint pr4[4] = {pk.x, pk.y, pk.z, pk.w};
                #pragma unroll
                for (int nt = 0; nt < 4; ++nt) {
                    const ushort* xb = xbase + nt * 2048;
                    float prods[8];
                    #pragma unroll
                    for (int e = 0; e < 8; ++e) {
                        const uint ent = (pr4[e >> 1] >> ((e & 1) * 16)) & 0xFFFFu;
                        prods[e] = h2f(xb[(int)(ent & 0xFFu) ^ sw]) *
                                   h2f(xb[(int)(ent >> 8) ^ sw]);
                    }
                    union { half8 h; uint wdw[4]; } bb;
                    #pragma unroll
                    for (int p = 0; p < 4; ++p) {
                        const auto pk2 = __builtin_amdgcn_cvt_pkrtz(
                            prods[2 * p], prods[2 * p + 1]);
                        __builtin_memcpy(&bb.wdw[p], &pk2, 4);
                    }
                    const half8 bfr = bb.h;
                    #pragma unroll
                    for (int mt = 0; mt < 4; ++mt)
                        acc[mt][nt] = __builtin_amdgcn_mfma_f32_16x16x32_f16(
                            af[kk * 4 + mt], bfr, acc[mt][nt], 0, 0, 0);
                }
            }
        }
    }

    // ---- epilogue: atomic accumulate (C/D: col=lane&15, row=quad*4+reg) ----
    #pragma unroll
    for (int mt = 0; mt < 4; ++mt) {
        #pragma unroll
        for (int nt = 0; nt < 4; ++nt) {
            const int mbase = wm * 64 + mt * 16 + quad * 4;
            const size_t col = (size_t)b0 + wn * 64 + nt * 16 + l16;
            #pragma unroll
            for (int r = 0; r < 4; ++r)
                unsafeAtomicAdd(&out[(size_t)(mbase + r) * BATCH_ + col],
                                acc[mt][nt][r]);
        }
    }
}

extern "C" void kernel_launch(void* const* d_in, const int* in_sizes, int n_in,
                              void* d_out, int out_size, void* d_ws, size_t ws_size,
                              hipStream_t stream) {
    const float* x = (const float*)d_in[0];   // [128, 16384]
    const float* A = (const float*)d_in[1];   // [128, 128]
    const float* B = (const float*)d_in[2];   // [128, 8256]
    float* out = (float*)d_out;               // [128, 16384]

    ushort* wt = (ushort*)d_ws;
    ushort* pp = (ushort*)((char*)d_ws + PP_OFF);
    ushort* xh = (ushort*)((char*)d_ws + XH_OFF);

    build_all<<<845, 256, 0, stream>>>(x, A, B, pp, wt, xh, out);
    gemm_mfma<<<dim3(BATCH_ / 256, 4), 512, 0, stream>>>(xh, wt, pp, out);
}